// Round 6
// baseline (247.599 us; speedup 1.0000x reference)
//
#include <hip/hip_runtime.h>
#include <math.h>

#define N_TOK 8192
#define DIM   4096
#define NE    16
#define TOKS  (2*N_TOK)        // 16384
#define NCHUNK (TOKS/64)       // 256
#define D4    (DIM/4)          // 1024 float4 per row
#define NSEG  4                // D segments (1024 cols = 256 f4 each)
#define SEGF4 (D4/NSEG)        // 256

// d_out layout (all float32):
// [0] l_aux | [1..16384] token_pos_after | [16385..32768] token_pos_before
// [32769..32784] expert_token_count | [32785..49168] weight
#define OUT_LAUX 0
#define OUT_TPA  1
#define OUT_TPB  (1+TOKS)
#define OUT_CNT  (1+2*TOKS)
#define OUT_W    (1+2*TOKS+NE)

// K1: partial logits. 1024 blocks x 512 threads. Block = 32 rows x one
// 1024-col D-segment. Wg segment (64 KB) staged to LDS once per block
// (ONE barrier, no in-loop barriers). Wave = 4 rows; all 16 x float4-loads
// issued upfront (independent -> max misses in flight); FMA loop reads Wg
// exclusively from LDS (zero in-loop vmem beyond the 16 x loads).
__global__ __launch_bounds__(512) void k1_logits(
    const float4* __restrict__ x4, const float4* __restrict__ wg4,
    float* __restrict__ part)
{
    __shared__ float4 wgs[NE][SEGF4];   // 64 KB

    const int tid  = threadIdx.x;
    const int lane = tid & 63;
    const int w    = tid >> 6;          // 0..7
    const int seg  = blockIdx.x & 3;
    const int rg   = blockIdx.x >> 2;   // row group of 32
    const int row0 = rg * 32 + w * 4;

    // stage Wg segment: 4096 f4, 8 per thread, coalesced
    #pragma unroll
    for (int i = 0; i < 8; ++i) {
        const int idx = i * 512 + tid;
        wgs[idx >> 8][idx & 255] = wg4[(size_t)(idx >> 8) * D4 + seg * SEGF4 + (idx & 255)];
    }

    // issue ALL 16 x loads before the barrier (independent of LDS)
    float4 xq[4][4];   // [j][r]
    #pragma unroll
    for (int j = 0; j < 4; ++j)
        #pragma unroll
        for (int r = 0; r < 4; ++r)
            xq[j][r] = x4[(size_t)(row0 + r) * D4 + seg * SEGF4 + j * 64 + lane];

    __syncthreads();   // wgs ready

    float acc[4][NE];
    #pragma unroll
    for (int r = 0; r < 4; ++r)
        #pragma unroll
        for (int e = 0; e < NE; ++e) acc[r][e] = 0.f;

    #pragma unroll
    for (int j = 0; j < 4; ++j) {
        #pragma unroll
        for (int e = 0; e < NE; ++e) {
            const float4 wv = wgs[e][j * 64 + lane];
            #pragma unroll
            for (int r = 0; r < 4; ++r) {
                acc[r][e] = fmaf(xq[j][r].x, wv.x, acc[r][e]);
                acc[r][e] = fmaf(xq[j][r].y, wv.y, acc[r][e]);
                acc[r][e] = fmaf(xq[j][r].z, wv.z, acc[r][e]);
                acc[r][e] = fmaf(xq[j][r].w, wv.w, acc[r][e]);
            }
        }
    }

    // per-(r,e) butterfly: all lanes end with the segment total (spill-free)
    #pragma unroll
    for (int r = 0; r < 4; ++r)
        #pragma unroll
        for (int e = 0; e < NE; ++e) {
            float v = acc[r][e];
            v += __shfl_xor(v, 32); v += __shfl_xor(v, 16);
            v += __shfl_xor(v, 8);  v += __shfl_xor(v, 4);
            v += __shfl_xor(v, 2);  v += __shfl_xor(v, 1);
            acc[r][e] = v;
        }

    // lane r (r<4) stores row0+r's 16 partials as 4 float4 (vector stores)
    if (lane < 4) {
        const int r = lane;
        float4* p4 = (float4*)part;
        const size_t base = ((size_t)seg * N_TOK + row0 + r) * 4;
        p4[base + 0] = make_float4(acc[r][0],  acc[r][1],  acc[r][2],  acc[r][3]);
        p4[base + 1] = make_float4(acc[r][4],  acc[r][5],  acc[r][6],  acc[r][7]);
        p4[base + 2] = make_float4(acc[r][8],  acc[r][9],  acc[r][10], acc[r][11]);
        p4[base + 3] = make_float4(acc[r][12], acc[r][13], acc[r][14], acc[r][15]);
    }
}

// K2: combine 4 segment partials (fixed order -> deterministic), top-2,
// softmax, weights, me partials, stable intra-chunk ranks + chunk histograms.
// 64 blocks x 128 threads, one thread per row. Wave = one 64-row chunk.
__global__ __launch_bounds__(128) void k2_route(
    const float* __restrict__ part, int* __restrict__ pr,
    int* __restrict__ hist, float* __restrict__ me_part,
    float* __restrict__ out)
{
    const int row   = blockIdx.x * 128 + threadIdx.x;
    const int lane  = threadIdx.x & 63;
    const int gwave = row >> 6;   // chunk index for top-1 half, in [0,128)

    float lg[NE];
    #pragma unroll
    for (int e = 0; e < NE; ++e) lg[e] = 0.f;
    const float4* p4 = (const float4*)part;
    #pragma unroll
    for (int s = 0; s < NSEG; ++s) {
        const size_t base = ((size_t)s * N_TOK + row) * 4;
        #pragma unroll
        for (int q = 0; q < 4; ++q) {
            float4 t = p4[base + q];
            lg[q * 4 + 0] += t.x;
            lg[q * 4 + 1] += t.y;
            lg[q * 4 + 2] += t.z;
            lg[q * 4 + 3] += t.w;
        }
    }

    // top-2; strict > keeps lowest index on ties (matches lax.top_k)
    float m1 = -INFINITY; int i1 = 0;
    #pragma unroll
    for (int e = 0; e < NE; ++e)
        if (lg[e] > m1) { m1 = lg[e]; i1 = e; }
    float m2 = -INFINITY; int i2 = 0;
    #pragma unroll
    for (int e = 0; e < NE; ++e)
        if (e != i1 && lg[e] > m2) { m2 = lg[e]; i2 = e; }

    float ssum = 0.f, ex[NE];
    #pragma unroll
    for (int e = 0; e < NE; ++e) { ex[e] = __expf(lg[e] - m1); ssum += ex[e]; }
    const float inv = 1.f / ssum;

    const float e2v = __expf(m2 - m1);
    const float w1  = 1.f / (1.f + e2v);
    out[OUT_W + row]         = w1;
    out[OUT_W + N_TOK + row] = 1.f - w1;

    // per-wave me partial: butterfly each expert; lane e keeps expert e's sum
    float mymev = 0.f;
    #pragma unroll
    for (int e = 0; e < NE; ++e) {
        float mv = ex[e] * inv;
        mv += __shfl_xor(mv, 32); mv += __shfl_xor(mv, 16);
        mv += __shfl_xor(mv, 8);  mv += __shfl_xor(mv, 4);
        mv += __shfl_xor(mv, 2);  mv += __shfl_xor(mv, 1);
        if (lane == e) mymev = mv;
    }
    if (lane < NE) me_part[gwave * NE + lane] = mymev;

    // stable intra-chunk ranks + chunk histograms via ballot
    const unsigned long long mlt = (1ull << lane) - 1ull;
    int rk1 = 0, rk2 = 0;
    #pragma unroll
    for (int eo = 0; eo < NE; ++eo) {
        unsigned long long mA = __ballot(i1 == eo);
        unsigned long long mB = __ballot(i2 == eo);
        if (i1 == eo) rk1 = (int)__popcll(mA & mlt);
        if (i2 == eo) rk2 = (int)__popcll(mB & mlt);
        if (lane == eo) {
            hist[gwave * NE + eo]                = (int)__popcll(mA);
            hist[(NCHUNK / 2 + gwave) * NE + eo] = (int)__popcll(mB);
        }
    }
    pr[row]         = i1 | (rk1 << 8);
    pr[N_TOK + row] = i2 | (rk2 << 8);
}

// K3: 64 blocks x 256. Every block redundantly scans the 256x16 chunk
// histogram in LDS, then places its 256 tokens. Block 0 adds l_aux + counts.
__global__ __launch_bounds__(256) void k3_place(
    const int* __restrict__ pr, const int* __restrict__ hist,
    const float* __restrict__ me_part, float* __restrict__ out)
{
    __shared__ int   sh[NCHUNK][20];   // padded
    __shared__ int   cnt_sh[NE], ce_sh[NE];
    __shared__ float me_sh[16][17];
    __shared__ float me_tot[NE];

    const int t = threadIdx.x;

    int h[NE];
    {
        const int4* h4 = (const int4*)(hist + t * NE);
        int4 a = h4[0], b = h4[1], c = h4[2], d = h4[3];
        h[0]=a.x; h[1]=a.y; h[2]=a.z; h[3]=a.w;
        h[4]=b.x; h[5]=b.y; h[6]=b.z; h[7]=b.w;
        h[8]=c.x; h[9]=c.y; h[10]=c.z; h[11]=c.w;
        h[12]=d.x; h[13]=d.y; h[14]=d.z; h[15]=d.w;
    }
    #pragma unroll
    for (int e = 0; e < NE; ++e) sh[t][e] = h[e];
    __syncthreads();

    for (int off = 1; off < NCHUNK; off <<= 1) {
        int tmp[NE];
        #pragma unroll
        for (int e = 0; e < NE; ++e) tmp[e] = (t >= off) ? sh[t - off][e] : 0;
        __syncthreads();
        #pragma unroll
        for (int e = 0; e < NE; ++e) sh[t][e] += tmp[e];
        __syncthreads();
    }

    if (t == NCHUNK - 1) {
        #pragma unroll
        for (int e = 0; e < NE; ++e) cnt_sh[e] = sh[t][e];
    }
    if (t == NCHUNK / 2 - 1) {
        #pragma unroll
        for (int e = 0; e < NE; ++e) ce_sh[e] = sh[t][e];  // top-1 totals
    }

    int ex[NE];
    #pragma unroll
    for (int e = 0; e < NE; ++e) ex[e] = sh[t][e] - h[e];
    __syncthreads();
    #pragma unroll
    for (int e = 0; e < NE; ++e) sh[t][e] = ex[e];
    __syncthreads();

    int offs[NE];
    {
        int run = 0;
        #pragma unroll
        for (int e = 0; e < NE; ++e) { offs[e] = run; run += cnt_sh[e]; }
    }

    {
        const int tk = blockIdx.x * 256 + t;
        const int v  = pr[tk];
        const int e  = v & 255;
        const int rk = v >> 8;
        const int c  = tk >> 6;
        const int pos = sh[c][e] + offs[e] + rk;
        out[OUT_TPA + tk]  = (float)pos;
        out[OUT_TPB + pos] = (float)tk;
    }

    if (blockIdx.x == 0) {
        {
            const int e = t & 15, gg = t >> 4;   // gg in [0,16)
            float s = 0.f;
            #pragma unroll
            for (int k = 0; k < 8; ++k) s += me_part[(gg + 16 * k) * NE + e];
            me_sh[gg][e] = s;
        }
        __syncthreads();
        if (t < NE) {
            float me = 0.f;
            #pragma unroll
            for (int gg = 0; gg < 16; ++gg) me += me_sh[gg][t];
            me_tot[t] = me;
            out[OUT_CNT + t] = (float)cnt_sh[t];
        }
        __syncthreads();
        if (t == 0) {
            float la = 0.f;
            #pragma unroll
            for (int e = 0; e < NE; ++e)
                la += (me_tot[e] * (1.0f / N_TOK)) * ((float)ce_sh[e] * (1.0f / N_TOK));
            out[OUT_LAUX] = la * (float)NE;
        }
    }
}

extern "C" void kernel_launch(void* const* d_in, const int* in_sizes, int n_in,
                              void* d_out, int out_size, void* d_ws, size_t ws_size,
                              hipStream_t stream) {
    const float* x  = (const float*)d_in[0];   // [8192,4096] fp32
    const float* wg = (const float*)d_in[1];   // [16,4096] fp32
    float* out = (float*)d_out;

    char* w = (char*)d_ws;
    float* part    = (float*)w;  w += (size_t)NSEG * N_TOK * NE * sizeof(float); // 2 MB
    int*   pr      = (int*)w;    w += TOKS * sizeof(int);         // 64 KB
    int*   hist    = (int*)w;    w += NCHUNK * NE * sizeof(int);  // 16 KB
    float* me_part = (float*)w;                                   // 8 KB

    k1_logits<<<(N_TOK / 32) * NSEG, 512, 0, stream>>>(
        (const float4*)x, (const float4*)wg, part);
    k2_route<<<N_TOK / 128, 128, 0, stream>>>(part, pr, hist, me_part, out);
    k3_place<<<TOKS / 256, 256, 0, stream>>>(pr, hist, me_part, out);
}